// Round 1
// baseline (234.713 us; speedup 1.0000x reference)
//
#include <hip/hip_runtime.h>

// BEV pooling (Lift-Splat-Shoot voxel scatter-add), MI355X / gfx950.
// x:    (1, 6, 112, 16, 44, 80) f32  -> flat (Nprime=473088, C=80)
// geom: (1, 6, 112, 16, 44, 3)  i32  -> flat (Nprime, 3)
// out:  (1, C=80, NZ=16, NX=128, NY=128) f32  (zero-filled, scatter-added)

#define BNX 128
#define BNY 128
#define BNZ 16
#define BC  80
#define QUADS (BC / 4)          // 20 float4 quads per point
#define CH_STRIDE (BNZ * BNX * BNY)  // 262144 floats between channel planes

__global__ __launch_bounds__(256) void lss_scatter_kernel(
    const float* __restrict__ x,
    const int* __restrict__ geom,
    float* __restrict__ out,
    int npoints)
{
    int gid = blockIdx.x * blockDim.x + threadIdx.x;
    int p = gid / QUADS;          // point index (20 consecutive threads/point)
    int q = gid - p * QUADS;      // which float4 quad of the 80 channels
    if (p >= npoints) return;

    // geom load: 20 threads of a point read the same 3 ints -> L1 broadcast
    int gx = geom[p * 3 + 0];
    int gy = geom[p * 3 + 1];
    int gz = geom[p * 3 + 2];

    // bounds test BEFORE loading x: ~88% of points rejected, their x rows
    // (320B contiguous) are never fetched from HBM.
    if ((unsigned)gx >= (unsigned)BNX ||
        (unsigned)gy >= (unsigned)BNY ||
        (unsigned)gz >= (unsigned)BNZ) return;

    // coalesced float4 load: 20 consecutive lanes cover one 320B point row
    const float4 v = *reinterpret_cast<const float4*>(&x[(size_t)p * BC + q * 4]);

    int base = gz * (BNX * BNY) + gx * BNY + gy;   // within-plane offset
    int c0 = q * 4;
    atomicAdd(&out[base + (c0 + 0) * CH_STRIDE], v.x);
    atomicAdd(&out[base + (c0 + 1) * CH_STRIDE], v.y);
    atomicAdd(&out[base + (c0 + 2) * CH_STRIDE], v.z);
    atomicAdd(&out[base + (c0 + 3) * CH_STRIDE], v.w);
}

extern "C" void kernel_launch(void* const* d_in, const int* in_sizes, int n_in,
                              void* d_out, int out_size, void* d_ws, size_t ws_size,
                              hipStream_t stream)
{
    const float* x   = (const float*)d_in[0];
    const int* geom  = (const int*)d_in[1];
    float* out       = (float*)d_out;

    const int npoints = in_sizes[0] / BC;   // 473088

    // Output must be exactly zero in untouched cells; harness poisons d_out
    // with 0xAA and does not re-zero between timed replays.
    hipMemsetAsync(d_out, 0, (size_t)out_size * sizeof(float), stream);

    const long long total = (long long)npoints * QUADS;
    const int block = 256;
    const int grid = (int)((total + block - 1) / block);
    lss_scatter_kernel<<<grid, block, 0, stream>>>(x, geom, out, npoints);
}

// Round 2
// 81.200 us; speedup vs baseline: 2.8906x; 2.8906x over previous
//
#include <hip/hip_runtime.h>

// BEV pooling (Lift-Splat-Shoot voxel pooling) as a GATHER, MI355X / gfx950.
//
// Reference semantics:
//   x:    (B=1, 6, 112, 16, 44, C=80) f32 -> flat (Nprime=473088, 80)
//   geom: (B=1, 6, 112, 16, 44, 3)    i32 -> flat (Nprime, 3)
//   out:  (B, C=80, NZ=16, NX=128, NY=128) f32
//   out[b][c][z][x][y] = sum of xf[p][c] over points p with geom==(x,y,z), in-bounds.
//
// Strategy: build per-voxel linked lists (head/next via atomicExch), then one
// thread per OUTPUT element walks its voxel's chain. Output written exactly
// once, fully coalesced; no output memset, no output atomics.

#define BNX 128
#define BNY 128
#define BNZ 16
#define BC  80
#define PLANE      (BNX * BNY)        // 16384
#define NSEG_PER_B (BNZ * PLANE)      // 262144 voxels per batch
#define ZX         (BNZ * BNX)        // 2048 (z,x) rows per batch

// ---- kernel 1: build voxel chains -----------------------------------------
__global__ __launch_bounds__(256) void build_chains(
    const int* __restrict__ geom,
    int* __restrict__ head,   // [B*NSEG_PER_B], pre-set to -1
    int* __restrict__ next,   // [npoints]
    int npoints, int per_b)
{
    int p = blockIdx.x * blockDim.x + threadIdx.x;
    if (p >= npoints) return;

    int gx = geom[p * 3 + 0];
    int gy = geom[p * 3 + 1];
    int gz = geom[p * 3 + 2];
    if ((unsigned)gx >= (unsigned)BNX ||
        (unsigned)gy >= (unsigned)BNY ||
        (unsigned)gz >= (unsigned)BNZ) return;

    int b = p / per_b;
    // within-batch cell id in OUTPUT spatial order: z-major, then x, then y
    int seg = b * NSEG_PER_B + gz * PLANE + gx * BNY + gy;
    int old = atomicExch(&head[seg], p);
    next[p] = old;
}

// ---- kernel 2: gather-sum, one thread per output element -------------------
// block = 128 threads (one (z,x) row of y's, one channel); grid = B*ZX*BC.
// Consecutive blocks vary c for fixed (z,x): the 80 sibling blocks reuse the
// same head row + chains + x rows while they're hot in L2/L3.
__global__ __launch_bounds__(128) void gather_sum(
    const float* __restrict__ x,
    const int* __restrict__ head,
    const int* __restrict__ next,
    float* __restrict__ out)
{
    int bid = blockIdx.x;
    int b   = bid / (ZX * BC);
    int r   = bid - b * (ZX * BC);
    int zx  = r / BC;            // z*128 + x
    int c   = r - zx * BC;       // channel
    int y   = threadIdx.x;

    int cell = zx * BNY + y;     // z*PLANE + x*BNY + y
    float sum = 0.f;
    int p = head[b * NSEG_PER_B + cell];
    while (p >= 0) {
        sum += x[(size_t)p * BC + c];
        p = next[p];
    }
    out[((size_t)b * BC + c) * NSEG_PER_B + cell] = sum;
}

extern "C" void kernel_launch(void* const* d_in, const int* in_sizes, int n_in,
                              void* d_out, int out_size, void* d_ws, size_t ws_size,
                              hipStream_t stream)
{
    const float* x  = (const float*)d_in[0];
    const int* geom = (const int*)d_in[1];
    float* out      = (float*)d_out;

    const int npoints = in_sizes[0] / BC;                 // 473088
    const int B       = out_size / (BC * NSEG_PER_B);     // 1
    const int per_b   = npoints / (B > 0 ? B : 1);
    const int nseg    = B * NSEG_PER_B;

    // workspace: head[nseg] then next[npoints]
    int* head = (int*)d_ws;
    int* next = head + nseg;

    // head = -1 everywhere (0xFF bytes)
    hipMemsetAsync(head, 0xFF, (size_t)nseg * sizeof(int), stream);

    build_chains<<<(npoints + 255) / 256, 256, 0, stream>>>(
        geom, head, next, npoints, per_b);

    const int nblk = B * ZX * BC;   // 163840
    gather_sum<<<nblk, 128, 0, stream>>>(x, head, next, out);
}

// Round 3
// 72.595 us; speedup vs baseline: 3.2332x; 1.1185x over previous
//
#include <hip/hip_runtime.h>

// BEV pooling (Lift-Splat-Shoot) as chains + row-gather, MI355X / gfx950.
//
//   x:    flat (Nprime=473088, C=80) f32
//   geom: flat (Nprime, 3) i32
//   out:  (B, C=80, NZ=16, NX=128, NY=128) f32
//   out[b][c][z][x][y] = sum of x[p][c] over in-bounds points p at (x,y,z).
//
// k1: per-voxel linked lists (head/next, atomicExch).
// k2: one block per (z,x) row: walk 128 chains -> LDS point list -> coalesced
//     x-row reads (80 lanes = one 320B row, read ONCE) -> LDS 128x80 acc tile
//     -> coalesced output store. No output atomics, no output memset.

#define BNX 128
#define BNY 128
#define BNZ 16
#define BC  80
#define PLANE      (BNX * BNY)     // 16384
#define NSEG_PER_B (BNZ * PLANE)   // 262144
#define ZX         (BNZ * BNX)     // 2048 rows per batch
#define CAP 768                    // LDS point-list capacity per batch (avg ~28)

// ---- kernel 1: build voxel chains -----------------------------------------
__global__ __launch_bounds__(256) void build_chains(
    const int* __restrict__ geom,
    int* __restrict__ head,   // [B*NSEG_PER_B], pre-set to -1
    int* __restrict__ next,   // [npoints]
    int npoints, int per_b)
{
    int p = blockIdx.x * blockDim.x + threadIdx.x;
    if (p >= npoints) return;

    int gx = geom[p * 3 + 0];
    int gy = geom[p * 3 + 1];
    int gz = geom[p * 3 + 2];
    if ((unsigned)gx >= (unsigned)BNX ||
        (unsigned)gy >= (unsigned)BNY ||
        (unsigned)gz >= (unsigned)BNZ) return;

    int b = p / per_b;
    int seg = b * NSEG_PER_B + gz * PLANE + gx * BNY + gy;
    int old = atomicExch(&head[seg], p);
    next[p] = old;
}

// ---- kernel 2: row gather --------------------------------------------------
// grid = B*ZX blocks, 256 threads. Block owns (b, z, x): cells y=0..127, all c.
__global__ __launch_bounds__(256) void gather_rows(
    const float* __restrict__ x,
    const int* __restrict__ head,
    const int* __restrict__ next,
    float* __restrict__ out)
{
    __shared__ float acc[BNY * BC];     // 40 KB: acc[y*80 + c]
    __shared__ int   list[CAP];         // packed p*128 + y
    __shared__ int   cnt;

    const int tid = threadIdx.x;
    const int b   = blockIdx.x / ZX;
    const int zx  = blockIdx.x - b * ZX;          // z*128 + x

    // zero the accumulator tile
    for (int i = tid; i < BNY * BC; i += 256) acc[i] = 0.f;

    // each of the first 128 threads owns one cell's chain
    int p = -1;
    if (tid < BNY) p = head[b * NSEG_PER_B + zx * BNY + tid];  // coalesced 512B

    const int c = tid % BC;            // for process phase (tid < 240)
    const int k = tid / BC;            // 0..2 point slot

    for (;;) {
        if (tid == 0) cnt = 0;
        __syncthreads();

        // push phase: drain chains into the LDS list (batched)
        while (p >= 0) {
            int idx = atomicAdd(&cnt, 1);
            if (idx >= CAP) break;                 // keep p for next batch
            list[idx] = p * BNY + tid;             // pack (p, y); p<2^25
            p = next[p];
        }
        __syncthreads();

        int n = cnt < CAP ? cnt : CAP;

        // process phase: 3 points x 80 channels per iteration, coalesced x rows
        if (tid < 240) {
            for (int i = k; i < n; i += 3) {
                int e  = list[i];
                int pp = e / BNY;
                int yy = e - pp * BNY;
                float v = x[(size_t)pp * BC + c];
                atomicAdd(&acc[yy * BC + c], v);   // LDS atomic, ~conflict-free
            }
        }
        __syncthreads();

        if (!__syncthreads_or(p >= 0 ? 1 : 0)) break;
    }

    // store phase: out[(b*C + c)*NSEG + zx*128 + y], coalesced 512B per c
    {
        const int y  = tid & 127;          // 0..127
        const int ch = tid >> 7;           // 0..1
        size_t base = (size_t)b * BC * NSEG_PER_B + (size_t)zx * BNY + y;
        for (int cc = ch; cc < BC; cc += 2)
            out[base + (size_t)cc * NSEG_PER_B] = acc[y * BC + cc];
    }
}

extern "C" void kernel_launch(void* const* d_in, const int* in_sizes, int n_in,
                              void* d_out, int out_size, void* d_ws, size_t ws_size,
                              hipStream_t stream)
{
    const float* x  = (const float*)d_in[0];
    const int* geom = (const int*)d_in[1];
    float* out      = (float*)d_out;

    const int npoints = in_sizes[0] / BC;                 // 473088
    const int B       = out_size / (BC * NSEG_PER_B);     // 1
    const int per_b   = npoints / (B > 0 ? B : 1);
    const int nseg    = B * NSEG_PER_B;

    int* head = (int*)d_ws;
    int* next = head + nseg;

    hipMemsetAsync(head, 0xFF, (size_t)nseg * sizeof(int), stream);

    build_chains<<<(npoints + 255) / 256, 256, 0, stream>>>(
        geom, head, next, npoints, per_b);

    gather_rows<<<B * ZX, 256, 0, stream>>>(x, head, next, out);
}

// Round 4
// 58.031 us; speedup vs baseline: 4.0446x; 1.2510x over previous
//
#include <hip/hip_runtime.h>

// BEV pooling (Lift-Splat-Shoot) as chains + row-gather, MI355X / gfx950.
//
//   x:    flat (Nprime=473088, C=80) f32
//   geom: flat (Nprime, 3) i32
//   out:  (B, C=80, NZ=16, NX=128, NY=128) f32
//   out[b][c][z][x][y] = sum of x[p][c] over in-bounds points p at (x,y,z).
//
// k0: init head[] = -1 (custom kernel; rocclr fillBuffer was 88us for 1MB!)
// k1: per-voxel linked lists (head/next, atomicExch).
// k2: one block per (z,x) row: walk 128 chains -> LDS point list -> coalesced
//     x-row reads (80 lanes = one 320B row, read ONCE) -> LDS 128x81-padded
//     acc tile -> coalesced output store. No output atomics, no output memset.

#define BNX 128
#define BNY 128
#define BNZ 16
#define BC  80
#define ACCP 81                    // padded acc stride: bank=(17y+c)%32, full spread
#define PLANE      (BNX * BNY)     // 16384
#define NSEG_PER_B (BNZ * PLANE)   // 262144
#define ZX         (BNZ * BNX)     // 2048 rows per batch
#define CAP 768                    // LDS point-list capacity per batch (avg ~28)

// ---- kernel 0: head = -1 ---------------------------------------------------
__global__ __launch_bounds__(256) void init_head(int4* __restrict__ head4, int n4)
{
    int i = blockIdx.x * blockDim.x + threadIdx.x;
    if (i < n4) head4[i] = make_int4(-1, -1, -1, -1);
}

// ---- kernel 1: build voxel chains -----------------------------------------
__global__ __launch_bounds__(256) void build_chains(
    const int* __restrict__ geom,
    int* __restrict__ head,   // [B*NSEG_PER_B], pre-set to -1
    int* __restrict__ next,   // [npoints]
    int npoints, int per_b)
{
    int p = blockIdx.x * blockDim.x + threadIdx.x;
    if (p >= npoints) return;

    int gx = geom[p * 3 + 0];
    int gy = geom[p * 3 + 1];
    int gz = geom[p * 3 + 2];
    if ((unsigned)gx >= (unsigned)BNX ||
        (unsigned)gy >= (unsigned)BNY ||
        (unsigned)gz >= (unsigned)BNZ) return;

    int b = p / per_b;
    int seg = b * NSEG_PER_B + gz * PLANE + gx * BNY + gy;
    int old = atomicExch(&head[seg], p);
    next[p] = old;
}

// ---- kernel 2: row gather --------------------------------------------------
// grid = B*ZX blocks, 256 threads. Block owns (b, z, x): cells y=0..127, all c.
__global__ __launch_bounds__(256) void gather_rows(
    const float* __restrict__ x,
    const int* __restrict__ head,
    const int* __restrict__ next,
    float* __restrict__ out)
{
    __shared__ float acc[BNY * ACCP];   // 41.5 KB: acc[y*81 + c]
    __shared__ int   list[CAP];         // packed p*128 + y
    __shared__ int   cnt;

    const int tid = threadIdx.x;
    const int b   = blockIdx.x / ZX;
    const int zx  = blockIdx.x - b * ZX;          // z*128 + x

    // zero the accumulator tile
    for (int i = tid; i < BNY * ACCP; i += 256) acc[i] = 0.f;

    // each of the first 128 threads owns one cell's chain
    int p = -1;
    if (tid < BNY) p = head[b * NSEG_PER_B + zx * BNY + tid];  // coalesced 512B

    const int c = tid % BC;            // for process phase (tid < 240)
    const int k = tid / BC;            // 0..2 point slot

    for (;;) {
        if (tid == 0) cnt = 0;
        __syncthreads();

        // push phase: drain chains into the LDS list (batched)
        while (p >= 0) {
            int idx = atomicAdd(&cnt, 1);
            if (idx >= CAP) break;                 // keep p for next batch
            list[idx] = p * BNY + tid;             // pack (p, y); p<2^25
            p = next[p];
        }
        __syncthreads();

        int n = cnt < CAP ? cnt : CAP;

        // process phase: 3 points x 80 channels per iteration, coalesced x rows
        if (tid < 240) {
            for (int i = k; i < n; i += 3) {
                int e  = list[i];
                int pp = e / BNY;
                int yy = e - pp * BNY;
                float v = x[(size_t)pp * BC + c];
                atomicAdd(&acc[yy * ACCP + c], v); // LDS atomic, conflict-free
            }
        }
        __syncthreads();

        if (!__syncthreads_or(p >= 0 ? 1 : 0)) break;
    }

    // store phase: out[(b*C + c)*NSEG + zx*128 + y], coalesced 512B per c
    {
        const int y  = tid & 127;          // 0..127
        const int ch = tid >> 7;           // 0..1
        size_t base = (size_t)b * BC * NSEG_PER_B + (size_t)zx * BNY + y;
        for (int cc = ch; cc < BC; cc += 2)
            out[base + (size_t)cc * NSEG_PER_B] = acc[y * ACCP + cc];
    }
}

extern "C" void kernel_launch(void* const* d_in, const int* in_sizes, int n_in,
                              void* d_out, int out_size, void* d_ws, size_t ws_size,
                              hipStream_t stream)
{
    const float* x  = (const float*)d_in[0];
    const int* geom = (const int*)d_in[1];
    float* out      = (float*)d_out;

    const int npoints = in_sizes[0] / BC;                 // 473088
    const int B       = out_size / (BC * NSEG_PER_B);     // 1
    const int per_b   = npoints / (B > 0 ? B : 1);
    const int nseg    = B * NSEG_PER_B;

    int* head = (int*)d_ws;
    int* next = head + nseg;

    const int n4 = nseg / 4;
    init_head<<<(n4 + 255) / 256, 256, 0, stream>>>((int4*)head, n4);

    build_chains<<<(npoints + 255) / 256, 256, 0, stream>>>(
        geom, head, next, npoints, per_b);

    gather_rows<<<B * ZX, 256, 0, stream>>>(x, head, next, out);
}

// Round 5
// 55.365 us; speedup vs baseline: 4.2394x; 1.0482x over previous
//
#include <hip/hip_runtime.h>

// BEV pooling (Lift-Splat-Shoot) as chains + row-gather, MI355X / gfx950.
//
//   x:    flat (Nprime=473088, C=80) f32
//   geom: flat (Nprime, 3) i32
//   out:  (B, C=80, NZ=16, NX=128, NY=128) f32
//   out[b][c][z][x][y] = sum of x[p][c] over in-bounds points p at (x,y,z).
//
// k0: init head[] = -1 (custom; rocclr fillBuffer was 88us for 1MB)
// k1: per-voxel linked lists (head/next, atomicExch).
// k2: one block per (z,x) row, 512 threads (occupancy: 3 blk/CU LDS-bound ->
//     24 waves/CU). Walk 128 chains -> LDS point list -> coalesced x-row
//     reads (80 lanes = one 320B row, read ONCE) -> LDS 128x81 padded acc
//     tile -> nontemporal coalesced output store. No output atomics/memset.

#define BNX 128
#define BNY 128
#define BNZ 16
#define BC  80
#define ACCP 81                    // padded acc stride: bank=(17y+c)%32, full spread
#define PLANE      (BNX * BNY)     // 16384
#define NSEG_PER_B (BNZ * PLANE)   // 262144
#define ZX         (BNZ * BNX)     // 2048 rows per batch
#define CAP 768                    // LDS point-list capacity per batch (avg ~28)
#define GT 512                     // gather block size

// ---- kernel 0: head = -1 ---------------------------------------------------
__global__ __launch_bounds__(256) void init_head(int4* __restrict__ head4, int n4)
{
    int i = blockIdx.x * blockDim.x + threadIdx.x;
    if (i < n4) head4[i] = make_int4(-1, -1, -1, -1);
}

// ---- kernel 1: build voxel chains -----------------------------------------
__global__ __launch_bounds__(256) void build_chains(
    const int* __restrict__ geom,
    int* __restrict__ head,   // [B*NSEG_PER_B], pre-set to -1
    int* __restrict__ next,   // [npoints]
    int npoints, int per_b)
{
    int p = blockIdx.x * blockDim.x + threadIdx.x;
    if (p >= npoints) return;

    int gx = geom[p * 3 + 0];
    int gy = geom[p * 3 + 1];
    int gz = geom[p * 3 + 2];
    if ((unsigned)gx >= (unsigned)BNX ||
        (unsigned)gy >= (unsigned)BNY ||
        (unsigned)gz >= (unsigned)BNZ) return;

    int b = p / per_b;
    int seg = b * NSEG_PER_B + gz * PLANE + gx * BNY + gy;
    int old = atomicExch(&head[seg], p);
    next[p] = old;
}

// ---- kernel 2: row gather --------------------------------------------------
// grid = B*ZX blocks, 512 threads. Block owns (b, z, x): cells y=0..127, all c.
__global__ __launch_bounds__(GT) void gather_rows(
    const float* __restrict__ x,
    const int* __restrict__ head,
    const int* __restrict__ next,
    float* __restrict__ out)
{
    __shared__ float acc[BNY * ACCP];   // 41.5 KB: acc[y*81 + c]
    __shared__ int   list[CAP];         // packed p*128 + y
    __shared__ int   cnt;

    const int tid = threadIdx.x;
    const int b   = blockIdx.x / ZX;
    const int zx  = blockIdx.x - b * ZX;          // z*128 + x

    // zero the accumulator tile
    for (int i = tid; i < BNY * ACCP; i += GT) acc[i] = 0.f;

    // each of the first 128 threads owns one cell's chain
    int p = -1;
    if (tid < BNY) p = head[b * NSEG_PER_B + zx * BNY + tid];  // coalesced 512B

    const int c = tid % BC;            // process-phase channel (tid < 480)
    const int k = tid / BC;            // 0..5 point slot

    for (;;) {
        if (tid == 0) cnt = 0;
        __syncthreads();

        // push phase: drain chains into the LDS list (batched)
        while (p >= 0) {
            int idx = atomicAdd(&cnt, 1);
            if (idx >= CAP) break;                 // keep p for next batch
            list[idx] = p * BNY + tid;             // pack (p, y); p<2^25
            p = next[p];
        }
        __syncthreads();

        int n = cnt < CAP ? cnt : CAP;

        // process phase: 6 points x 80 channels per iteration, coalesced x rows
        if (tid < 480) {
            for (int i = k; i < n; i += 6) {
                int e  = list[i];
                int pp = e / BNY;
                int yy = e - pp * BNY;
                float v = x[(size_t)pp * BC + c];
                atomicAdd(&acc[yy * ACCP + c], v); // LDS atomic, conflict-free
            }
        }
        __syncthreads();

        if (!__syncthreads_or(p >= 0 ? 1 : 0)) break;
    }

    // store phase: out[(b*C + c)*NSEG + zx*128 + y], nontemporal, coalesced
    {
        const int y  = tid & 127;          // 0..127
        const int ch = tid >> 7;           // 0..3
        size_t base = (size_t)b * BC * NSEG_PER_B + (size_t)zx * BNY + y;
        for (int cc = ch; cc < BC; cc += 4)
            __builtin_nontemporal_store(acc[y * ACCP + cc],
                                        &out[base + (size_t)cc * NSEG_PER_B]);
    }
}

extern "C" void kernel_launch(void* const* d_in, const int* in_sizes, int n_in,
                              void* d_out, int out_size, void* d_ws, size_t ws_size,
                              hipStream_t stream)
{
    const float* x  = (const float*)d_in[0];
    const int* geom = (const int*)d_in[1];
    float* out      = (float*)d_out;

    const int npoints = in_sizes[0] / BC;                 // 473088
    const int B       = out_size / (BC * NSEG_PER_B);     // 1
    const int per_b   = npoints / (B > 0 ? B : 1);
    const int nseg    = B * NSEG_PER_B;

    int* head = (int*)d_ws;
    int* next = head + nseg;

    const int n4 = nseg / 4;
    init_head<<<(n4 + 255) / 256, 256, 0, stream>>>((int4*)head, n4);

    build_chains<<<(npoints + 255) / 256, 256, 0, stream>>>(
        geom, head, next, npoints, per_b);

    gather_rows<<<B * ZX, GT, 0, stream>>>(x, head, next, out);
}

// Round 7
// 55.097 us; speedup vs baseline: 4.2600x; 1.0049x over previous
//
#include <hip/hip_runtime.h>

// BEV pooling (Lift-Splat-Shoot) as chains + row-gather, MI355X / gfx950.
//
//   x:    flat (Nprime=473088, C=80) f32
//   geom: flat (Nprime, 3) i32
//   out:  (B, C=80, NZ=16, NX=128, NY=128) f32
//   out[b][c][z][x][y] = sum of x[p][c] over in-bounds points p at (x,y,z).
//
// k0: init head[] = -1 (custom; rocclr fillBuffer was 88us for 1MB)
// k1: per-voxel linked lists (head/next, atomicExch).
// k2: one block per (z,x) row, 512 threads. Walk 128 chains -> LDS point
//     list -> coalesced x-row reads (80 lanes = one 320B row, read ONCE)
//     -> LDS 128x81 padded acc tile -> FLOAT4 nontemporal coalesced store
//     (16B/lane; scalar 4B/lane stores were the prior bottleneck).

#define BNX 128
#define BNY 128
#define BNZ 16
#define BC  80
#define ACCP 81                    // padded acc stride: bank=(17y+c)%32, full spread
#define PLANE      (BNX * BNY)     // 16384
#define NSEG_PER_B (BNZ * PLANE)   // 262144
#define ZX         (BNZ * BNX)     // 2048 rows per batch
#define CAP 768                    // LDS point-list capacity per batch (avg ~28)
#define GT 512                     // gather block size

typedef float fvec4 __attribute__((ext_vector_type(4)));  // nontemporal-store-able

// ---- kernel 0: head = -1 ---------------------------------------------------
__global__ __launch_bounds__(256) void init_head(int4* __restrict__ head4, int n4)
{
    int i = blockIdx.x * blockDim.x + threadIdx.x;
    if (i < n4) head4[i] = make_int4(-1, -1, -1, -1);
}

// ---- kernel 1: build voxel chains -----------------------------------------
__global__ __launch_bounds__(256) void build_chains(
    const int* __restrict__ geom,
    int* __restrict__ head,   // [B*NSEG_PER_B], pre-set to -1
    int* __restrict__ next,   // [npoints]
    int npoints, int per_b)
{
    int p = blockIdx.x * blockDim.x + threadIdx.x;
    if (p >= npoints) return;

    int gx = geom[p * 3 + 0];
    int gy = geom[p * 3 + 1];
    int gz = geom[p * 3 + 2];
    if ((unsigned)gx >= (unsigned)BNX ||
        (unsigned)gy >= (unsigned)BNY ||
        (unsigned)gz >= (unsigned)BNZ) return;

    int b = p / per_b;
    int seg = b * NSEG_PER_B + gz * PLANE + gx * BNY + gy;
    int old = atomicExch(&head[seg], p);
    next[p] = old;
}

// ---- kernel 2: row gather --------------------------------------------------
// grid = B*ZX blocks, 512 threads. Block owns (b, z, x): cells y=0..127, all c.
__global__ __launch_bounds__(GT) void gather_rows(
    const float* __restrict__ x,
    const int* __restrict__ head,
    const int* __restrict__ next,
    float* __restrict__ out)
{
    __shared__ float acc[BNY * ACCP];   // 41.5 KB: acc[y*81 + c]
    __shared__ int   list[CAP];         // packed p*128 + y
    __shared__ int   cnt;

    const int tid = threadIdx.x;
    const int b   = blockIdx.x / ZX;
    const int zx  = blockIdx.x - b * ZX;          // z*128 + x

    // zero the accumulator tile
    for (int i = tid; i < BNY * ACCP; i += GT) acc[i] = 0.f;

    // each of the first 128 threads owns one cell's chain
    int p = -1;
    if (tid < BNY) p = head[b * NSEG_PER_B + zx * BNY + tid];  // coalesced 512B

    const int c = tid % BC;            // process-phase channel (tid < 480)
    const int k = tid / BC;            // 0..5 point slot

    for (;;) {
        if (tid == 0) cnt = 0;
        __syncthreads();

        // push phase: drain chains into the LDS list (batched)
        while (p >= 0) {
            int idx = atomicAdd(&cnt, 1);
            if (idx >= CAP) break;                 // keep p for next batch
            list[idx] = p * BNY + tid;             // pack (p, y); p<2^25
            p = next[p];
        }
        __syncthreads();

        int n = cnt < CAP ? cnt : CAP;

        // process phase: 6 points x 80 channels per iteration, coalesced x rows
        if (tid < 480) {
            for (int i = k; i < n; i += 6) {
                int e  = list[i];
                int pp = e / BNY;
                int yy = e - pp * BNY;
                float v = x[(size_t)pp * BC + c];
                atomicAdd(&acc[yy * ACCP + c], v); // LDS atomic, conflict-free
            }
        }
        __syncthreads();

        if (!__syncthreads_or(p >= 0 ? 1 : 0)) break;
    }

    // store phase: float4 per thread. thread -> (channel cc, y-quad l).
    // 32 lanes x 16B = one full 512B y-row per channel, nontemporal.
    {
        const int l  = tid & 31;           // y-quad index: y = 4l..4l+3
        const int c0 = tid >> 5;           // 0..15
        size_t rowbase = (size_t)b * BC * NSEG_PER_B + (size_t)zx * BNY + 4 * l;
        for (int cc = c0; cc < BC; cc += 16) {
            fvec4 v;
            v.x = acc[(4 * l + 0) * ACCP + cc];
            v.y = acc[(4 * l + 1) * ACCP + cc];
            v.z = acc[(4 * l + 2) * ACCP + cc];
            v.w = acc[(4 * l + 3) * ACCP + cc];
            __builtin_nontemporal_store(v,
                (fvec4*)&out[rowbase + (size_t)cc * NSEG_PER_B]);
        }
    }
}

extern "C" void kernel_launch(void* const* d_in, const int* in_sizes, int n_in,
                              void* d_out, int out_size, void* d_ws, size_t ws_size,
                              hipStream_t stream)
{
    const float* x  = (const float*)d_in[0];
    const int* geom = (const int*)d_in[1];
    float* out      = (float*)d_out;

    const int npoints = in_sizes[0] / BC;                 // 473088
    const int B       = out_size / (BC * NSEG_PER_B);     // 1
    const int per_b   = npoints / (B > 0 ? B : 1);
    const int nseg    = B * NSEG_PER_B;

    int* head = (int*)d_ws;
    int* next = head + nseg;

    const int n4 = nseg / 4;
    init_head<<<(n4 + 255) / 256, 256, 0, stream>>>((int4*)head, n4);

    build_chains<<<(npoints + 255) / 256, 256, 0, stream>>>(
        geom, head, next, npoints, per_b);

    gather_rows<<<B * ZX, GT, 0, stream>>>(x, head, next, out);
}